// Round 22
// baseline (1224.920 us; speedup 1.0000x reference)
//
#include <hip/hip_runtime.h>

__global__ void GraphCNN_48679159333670_kernel() {}

__device__ __forceinline__ int rdi(const int* p, int pos, int f64) {
    return f64 ? p[2 * pos] : p[pos];
}

__global__ void k_mark(float* out, float v) {
    int i = blockIdx.x * 64 + threadIdx.x;
    if (i < 1024) out[i] = v;
}
__global__ void k_detect(const int* ei, int* flag) {
    if (threadIdx.x == 0) {
        int nz = 0;
        for (int k = 0; k < 256; ++k) nz += (ei[2 * k + 1] != 0);
        flag[0] = (nz == 0);
    }
}
__global__ void k_zero(int* p, int n) {
    int i = blockIdx.x * 256 + threadIdx.x;
    if (i < n) p[i] = 0;
}
__global__ void k_count(const int* ei, int* cnt, const int* flag, int ne, int nn) {
    int i = blockIdx.x * 256 + threadIdx.x;
    if (i < ne) {
        unsigned d = (unsigned)rdi(ei, ne + i, flag[0]);
        if (d < (unsigned)nn) atomicAdd(&cnt[d], 1);
    }
}
// single-block exclusive scan of cnt -> rowp, plus dis = rsqrt(deg+1)
__global__ void k_scan(const int* cnt, int* rowp, float* dis, int nn) {
    __shared__ int part[1024];
    int t = threadIdx.x;
    int ch = (nn + 1023) / 1024;
    int base = t * ch, sum = 0;
    for (int k = 0; k < ch; ++k) {
        int i = base + k;
        if (i < nn) sum += cnt[i];
    }
    part[t] = sum;
    __syncthreads();
    for (int off = 1; off < 1024; off <<= 1) {
        int v = (t >= off) ? part[t - off] : 0;
        __syncthreads();
        part[t] += v;
        __syncthreads();
    }
    int run = (t == 0) ? 0 : part[t - 1];
    for (int k = 0; k < ch; ++k) {
        int i = base + k;
        if (i < nn) {
            int c = cnt[i];
            rowp[i] = run;
            run += c;
            dis[i] = rsqrtf((float)c + 1.0f);
        }
    }
    if (t == 1023) rowp[nn] = run;
}
__global__ void k_fill(const int* ei, const int* rowp, int* cur, int* col,
                       const int* flag, int ne, int nn) {
    int i = blockIdx.x * 256 + threadIdx.x;
    if (i < ne) {
        int f = flag[0];
        unsigned s = (unsigned)rdi(ei, i, f);
        unsigned d = (unsigned)rdi(ei, ne + i, f);
        if (s < (unsigned)nn && d < (unsigned)nn)
            col[rowp[d] + atomicAdd(&cur[d], 1)] = (int)s;
    }
}
// H = X @ W ; X:[nn,K] f32, W:[K,64] row-major; 16 nodes/block
__global__ void k_mm(const float* X, const float* W, float* H, int nn, int K) {
    extern __shared__ float sm[];
    float* Wl = sm;
    float* Xl = sm + K * 64;
    int t = threadIdx.x;
    for (int idx = t; idx < K * 64; idx += 256) Wl[idx] = W[idx];
    int n0 = blockIdx.x * 16;
    for (int idx = t; idx < 16 * K; idx += 256) {
        int node = n0 + idx / K;
        Xl[idx] = (node < nn) ? X[(size_t)node * K + idx % K] : 0.f;
    }
    __syncthreads();
    int q = t & 15, nl = t >> 4;
    float a0 = 0, a1 = 0, a2 = 0, a3 = 0;
    for (int k = 0; k < K; ++k) {
        float xv = Xl[nl * K + k];
        const float* w = &Wl[k * 64 + q * 4];
        a0 += xv * w[0]; a1 += xv * w[1]; a2 += xv * w[2]; a3 += xv * w[3];
    }
    int node = n0 + nl;
    if (node < nn) {
        float* o = &H[(size_t)node * 64 + q * 4];
        o[0] = a0; o[1] = a1; o[2] = a2; o[3] = a3;
    }
}
// O = relu((sum_{s in N(i)} H[s]*dis[s] + H[i]*dis[i]) * dis[i] + b); 1 wave/node
__global__ void k_agg(const float* H, const int* col, const int* rowp,
                      const float* dis, const float* bias, float* O, int nn) {
    int i = blockIdx.x * 4 + (threadIdx.x >> 6);
    int lane = threadIdx.x & 63;
    if (i >= nn) return;
    int r0 = rowp[i], r1 = rowp[i + 1];
    float acc = 0.f;
    for (int j = r0; j < r1; ++j) {
        int s = col[j];
        acc += H[(size_t)s * 64 + lane] * dis[s];
    }
    float di = dis[i];
    acc += H[(size_t)i * 64 + lane] * di;
    O[(size_t)i * 64 + lane] = fmaxf(acc * di + bias[lane], 0.f);
}
// mean-pool over sorted batch ids; pool[g*64+c] sums, pool[4096+g] counts
__global__ void k_pool(const float* H, const int* batch, float* pool,
                       const int* flag, int nn) {
    int lane = threadIdx.x;
    int n0 = blockIdx.x * 256;
    if (n0 >= nn) return;
    int f = flag[0];
    int nend = (n0 + 256 < nn) ? n0 + 256 : nn;
    float acc = 0.f, cf = 0.f;
    int curg = rdi(batch, n0, f) & 63;
    for (int i = n0; i < nend; ++i) {
        int g = rdi(batch, i, f) & 63;
        if (g != curg) {
            atomicAdd(&pool[curg * 64 + lane], acc);
            if (lane == 0) atomicAdd(&pool[4096 + curg], cf);
            acc = 0.f; cf = 0.f; curg = g;
        }
        acc += H[(size_t)i * 64 + lane];
        cf += 1.f;
    }
    atomicAdd(&pool[curg * 64 + lane], acc);
    if (lane == 0) atomicAdd(&pool[4096 + curg], cf);
}
// MLP head + log_softmax; OUTPUT IS FLOAT32 (out_nbytes = out_size*4, proven r21)
__global__ void k_mlp(const float* pool, const float* fW1, const float* fb1,
                      const float* fW2, const float* fb2, float* out) {
    __shared__ float w1[2048], w2[512], b1s[32], b2s[16], gm[4096];
    int t = threadIdx.x;
    for (int i = t; i < 2048; i += 256) w1[i] = fW1[i];
    for (int i = t; i < 512; i += 256) w2[i] = fW2[i];
    if (t < 32) b1s[t] = fb1[t];
    if (t < 16) b2s[t] = fb2[t];
    for (int i = t; i < 4096; i += 256) {
        float c = pool[4096 + (i >> 6)];
        gm[i] = pool[i] / ((c < 1.f) ? 1.f : c);
    }
    __syncthreads();
    if (t < 64) {
        float hid[32], lg[16];
        for (int j = 0; j < 32; ++j) {
            float s = b1s[j];
            for (int k = 0; k < 64; ++k) s += gm[t * 64 + k] * w1[k * 32 + j];
            hid[j] = fmaxf(s, 0.f);
        }
        float m = -1e30f;
        for (int j = 0; j < 16; ++j) {
            float s = b2s[j];
            for (int k = 0; k < 32; ++k) s += hid[k] * w2[k * 16 + j];
            lg[j] = s;
            m = fmaxf(m, s);
        }
        float se = 0.f;
        for (int j = 0; j < 16; ++j) se += expf(lg[j] - m);
        float lse = m + logf(se);
        for (int j = 0; j < 16; ++j) out[t * 16 + j] = lg[j] - lse;
    }
}

extern "C" void kernel_launch(void* const* d_in, const int* in_sizes, int n_in,
                              void* d_out, int out_size, void* d_ws, size_t ws_size,
                              hipStream_t stream) {
    (void)in_sizes; (void)n_in; (void)out_size;
    const int nn = 100000, ne = 1600000;
    const float* x   = (const float*)d_in[0];
    const int*   ei  = (const int*)d_in[1];
    const int*   bat = (const int*)d_in[2];
    const float* W1  = (const float*)d_in[3];
    const float* b1  = (const float*)d_in[4];
    const float* W2  = (const float*)d_in[5];
    const float* b2  = (const float*)d_in[6];
    const float* W3  = (const float*)d_in[7];
    const float* b3  = (const float*)d_in[8];
    const float* fW1 = (const float*)d_in[9];
    const float* fb1 = (const float*)d_in[10];
    const float* fW2 = (const float*)d_in[11];
    const float* fb2 = (const float*)d_in[12];
    float* out = (float*)d_out;   // FLOAT32 output (r21: out_nbytes==4096)

    char* ws = (char*)d_ws;
    size_t o = 0;
    int*   cnt  = (int*)(ws + o);   o += 400128;     // nn*4, 256B-aligned
    float* pool = (float*)(ws + o); o += 16896;      // 64*64 sums + 64 counts
    size_t zints = o / 4;                            // cnt+pool zero region
    int*   rowp = (int*)(ws + o);   o += 400384;     // (nn+1)*4
    float* dis  = (float*)(ws + o); o += 400128;
    int*   flag = (int*)(ws + o);   o += 256;
    int*   col  = (int*)(ws + o);   o += 6400000;    // ne*4
    float* A    = (float*)(ws + o); o += 25600000;   // nn*64*4
    float* B    = (float*)(ws + o); o += 25600000;
    if (ws_size < o) {
        k_mark<<<16, 64, 0, stream>>>(out, 150.0f);  // error ~150: ws too small
        return;
    }

    int eb = (ne + 255) / 256, nb = (nn + 255) / 256;
    int mmb = (nn + 15) / 16, aggb = (nn + 3) / 4;

    k_detect<<<1, 64, 0, stream>>>(ei, flag);
    k_zero<<<((int)zints + 255) / 256, 256, 0, stream>>>((int*)ws, (int)zints);
    k_count<<<eb, 256, 0, stream>>>(ei, cnt, flag, ne, nn);
    k_scan<<<1, 1024, 0, stream>>>(cnt, rowp, dis, nn);
    k_zero<<<nb, 256, 0, stream>>>(cnt, nn);         // cnt -> fill cursor
    k_fill<<<eb, 256, 0, stream>>>(ei, rowp, cnt, col, flag, ne, nn);

    k_mm<<<mmb, 256, (128 * 64 + 16 * 128) * 4, stream>>>(x, W1, A, nn, 128);
    k_agg<<<aggb, 256, 0, stream>>>(A, col, rowp, dis, b1, B, nn);
    k_mm<<<mmb, 256, (64 * 64 + 16 * 64) * 4, stream>>>(B, W2, A, nn, 64);
    k_agg<<<aggb, 256, 0, stream>>>(A, col, rowp, dis, b2, B, nn);
    k_mm<<<mmb, 256, (64 * 64 + 16 * 64) * 4, stream>>>(B, W3, A, nn, 64);
    k_agg<<<aggb, 256, 0, stream>>>(A, col, rowp, dis, b3, B, nn);

    k_pool<<<nb, 64, 0, stream>>>(B, bat, pool, flag, nn);
    k_mlp<<<1, 256, 0, stream>>>(pool, fW1, fb1, fW2, fb2, out);
}

// Round 23
// 996.823 us; speedup vs baseline: 1.2288x; 1.2288x over previous
//
#include <hip/hip_runtime.h>

__global__ void GraphCNN_48679159333670_kernel() {}

__device__ __forceinline__ int rdi(const int* p, int pos, int f64) {
    return f64 ? p[2 * pos] : p[pos];
}

__global__ void k_mark(float* out, float v) {
    int i = blockIdx.x * 64 + threadIdx.x;
    if (i < 1024) out[i] = v;
}
__global__ void k_detect(const int* ei, int* flag) {
    if (threadIdx.x == 0) {
        int nz = 0;
        for (int k = 0; k < 256; ++k) nz += (ei[2 * k + 1] != 0);
        flag[0] = (nz == 0);
    }
}
__global__ void k_zero(int* p, int n) {
    int i = blockIdx.x * 256 + threadIdx.x;
    if (i < n) p[i] = 0;
}
__global__ void k_count(const int* ei, int* cnt, const int* flag, int ne, int nn) {
    int i = blockIdx.x * 256 + threadIdx.x;
    if (i < ne) {
        unsigned d = (unsigned)rdi(ei, ne + i, flag[0]);
        if (d < (unsigned)nn) atomicAdd(&cnt[d], 1);
    }
}
// hierarchical scan, stage 1: per-block (256) inclusive scan of cnt -> rowp[i+1],
// block total -> bsum[blockIdx]; also dis = rsqrt(deg+1)
__global__ void k_scan1(const int* cnt, int* rowp, int* bsum, float* dis, int nn) {
    __shared__ int s[256];
    int t = threadIdx.x;
    int i = blockIdx.x * 256 + t;
    int v = (i < nn) ? cnt[i] : 0;
    if (i < nn) dis[i] = rsqrtf((float)v + 1.0f);
    s[t] = v;
    __syncthreads();
    for (int off = 1; off < 256; off <<= 1) {
        int u = (t >= off) ? s[t - off] : 0;
        __syncthreads();
        s[t] += u;
        __syncthreads();
    }
    if (i < nn) rowp[i + 1] = s[t];
    if (t == 255) bsum[blockIdx.x] = s[t];
}
// stage 2: single block inclusive scan of the nb block sums (nb <= 512)
__global__ void k_scan2(int* bsum, int nb) {
    __shared__ int s[512];
    int t = threadIdx.x;
    s[t] = (t < nb) ? bsum[t] : 0;
    __syncthreads();
    for (int off = 1; off < 512; off <<= 1) {
        int u = (t >= off) ? s[t - off] : 0;
        __syncthreads();
        s[t] += u;
        __syncthreads();
    }
    if (t < nb) bsum[t] = s[t];
}
// stage 3: add block offsets; rowp[0] = 0
__global__ void k_scan3(int* rowp, const int* bsum, int nn) {
    int i = blockIdx.x * 256 + threadIdx.x;
    if (i == 0) rowp[0] = 0;
    if (i < nn) {
        int b = i >> 8;
        if (b > 0) rowp[i + 1] += bsum[b - 1];
    }
}
__global__ void k_fill(const int* ei, const int* rowp, int* cur, int* col,
                       const int* flag, int ne, int nn) {
    int i = blockIdx.x * 256 + threadIdx.x;
    if (i < ne) {
        int f = flag[0];
        unsigned s = (unsigned)rdi(ei, i, f);
        unsigned d = (unsigned)rdi(ei, ne + i, f);
        if (s < (unsigned)nn && d < (unsigned)nn)
            col[rowp[d] + atomicAdd(&cur[d], 1)] = (int)s;
    }
}
// H = X @ W ; X:[nn,K] f32, W:[K,64] row-major; 16 nodes/block
__global__ void k_mm(const float* X, const float* W, float* H, int nn, int K) {
    extern __shared__ float sm[];
    float* Wl = sm;
    float* Xl = sm + K * 64;
    int t = threadIdx.x;
    for (int idx = t; idx < K * 64; idx += 256) Wl[idx] = W[idx];
    int n0 = blockIdx.x * 16;
    for (int idx = t; idx < 16 * K; idx += 256) {
        int node = n0 + idx / K;
        Xl[idx] = (node < nn) ? X[(size_t)node * K + idx % K] : 0.f;
    }
    __syncthreads();
    int q = t & 15, nl = t >> 4;
    float a0 = 0, a1 = 0, a2 = 0, a3 = 0;
    for (int k = 0; k < K; ++k) {
        float xv = Xl[nl * K + k];
        const float* w = &Wl[k * 64 + q * 4];
        a0 += xv * w[0]; a1 += xv * w[1]; a2 += xv * w[2]; a3 += xv * w[3];
    }
    int node = n0 + nl;
    if (node < nn) {
        float* o = &H[(size_t)node * 64 + q * 4];
        o[0] = a0; o[1] = a1; o[2] = a2; o[3] = a3;
    }
}
// O = relu((sum_{s in N(i)} H[s]*dis[s] + H[i]*dis[i]) * dis[i] + b); 1 wave/node
__global__ void k_agg(const float* H, const int* col, const int* rowp,
                      const float* dis, const float* bias, float* O, int nn) {
    int i = blockIdx.x * 4 + (threadIdx.x >> 6);
    int lane = threadIdx.x & 63;
    if (i >= nn) return;
    int r0 = rowp[i], r1 = rowp[i + 1];
    float acc = 0.f;
    for (int j = r0; j < r1; ++j) {
        int s = col[j];
        acc += H[(size_t)s * 64 + lane] * dis[s];
    }
    float di = dis[i];
    acc += H[(size_t)i * 64 + lane] * di;
    O[(size_t)i * 64 + lane] = fmaxf(acc * di + bias[lane], 0.f);
}
// mean-pool over sorted batch ids; pool[g*64+c] sums, pool[4096+g] counts
__global__ void k_pool(const float* H, const int* batch, float* pool,
                       const int* flag, int nn) {
    int lane = threadIdx.x;
    int n0 = blockIdx.x * 256;
    if (n0 >= nn) return;
    int f = flag[0];
    int nend = (n0 + 256 < nn) ? n0 + 256 : nn;
    float acc = 0.f, cf = 0.f;
    int curg = rdi(batch, n0, f) & 63;
    for (int i = n0; i < nend; ++i) {
        int g = rdi(batch, i, f) & 63;
        if (g != curg) {
            atomicAdd(&pool[curg * 64 + lane], acc);
            if (lane == 0) atomicAdd(&pool[4096 + curg], cf);
            acc = 0.f; cf = 0.f; curg = g;
        }
        acc += H[(size_t)i * 64 + lane];
        cf += 1.f;
    }
    atomicAdd(&pool[curg * 64 + lane], acc);
    if (lane == 0) atomicAdd(&pool[4096 + curg], cf);
}
// MLP head + log_softmax; output f32
__global__ void k_mlp(const float* pool, const float* fW1, const float* fb1,
                      const float* fW2, const float* fb2, float* out) {
    __shared__ float w1[2048], w2[512], b1s[32], b2s[16], gm[4096];
    int t = threadIdx.x;
    for (int i = t; i < 2048; i += 256) w1[i] = fW1[i];
    for (int i = t; i < 512; i += 256) w2[i] = fW2[i];
    if (t < 32) b1s[t] = fb1[t];
    if (t < 16) b2s[t] = fb2[t];
    for (int i = t; i < 4096; i += 256) {
        float c = pool[4096 + (i >> 6)];
        gm[i] = pool[i] / ((c < 1.f) ? 1.f : c);
    }
    __syncthreads();
    if (t < 64) {
        float hid[32], lg[16];
        for (int j = 0; j < 32; ++j) {
            float s = b1s[j];
            for (int k = 0; k < 64; ++k) s += gm[t * 64 + k] * w1[k * 32 + j];
            hid[j] = fmaxf(s, 0.f);
        }
        float m = -1e30f;
        for (int j = 0; j < 16; ++j) {
            float s = b2s[j];
            for (int k = 0; k < 32; ++k) s += hid[k] * w2[k * 16 + j];
            lg[j] = s;
            m = fmaxf(m, s);
        }
        float se = 0.f;
        for (int j = 0; j < 16; ++j) se += expf(lg[j] - m);
        float lse = m + logf(se);
        for (int j = 0; j < 16; ++j) out[t * 16 + j] = lg[j] - lse;
    }
}

extern "C" void kernel_launch(void* const* d_in, const int* in_sizes, int n_in,
                              void* d_out, int out_size, void* d_ws, size_t ws_size,
                              hipStream_t stream) {
    (void)in_sizes; (void)n_in; (void)out_size;
    const int nn = 100000, ne = 1600000;
    const float* x   = (const float*)d_in[0];
    const int*   ei  = (const int*)d_in[1];
    const int*   bat = (const int*)d_in[2];
    const float* W1  = (const float*)d_in[3];
    const float* b1  = (const float*)d_in[4];
    const float* W2  = (const float*)d_in[5];
    const float* b2  = (const float*)d_in[6];
    const float* W3  = (const float*)d_in[7];
    const float* b3  = (const float*)d_in[8];
    const float* fW1 = (const float*)d_in[9];
    const float* fb1 = (const float*)d_in[10];
    const float* fW2 = (const float*)d_in[11];
    const float* fb2 = (const float*)d_in[12];
    float* out = (float*)d_out;   // FLOAT32 output (r21: out_nbytes==4096)

    char* ws = (char*)d_ws;
    size_t o = 0;
    int*   cnt  = (int*)(ws + o);   o += 400128;     // nn*4, 256B-aligned
    float* pool = (float*)(ws + o); o += 16896;      // 64*64 sums + 64 counts
    size_t zints = o / 4;                            // cnt+pool zero region
    int*   rowp = (int*)(ws + o);   o += 400384;     // (nn+1)*4
    int*   bsum = (int*)(ws + o);   o += 2048;       // 391 block sums
    float* dis  = (float*)(ws + o); o += 400128;
    int*   flag = (int*)(ws + o);   o += 256;
    int*   col  = (int*)(ws + o);   o += 6400000;    // ne*4
    float* A    = (float*)(ws + o); o += 25600000;   // nn*64*4
    float* B    = (float*)(ws + o); o += 25600000;
    if (ws_size < o) {
        k_mark<<<16, 64, 0, stream>>>(out, 150.0f);  // error ~150: ws too small
        return;
    }

    int eb = (ne + 255) / 256, nb = (nn + 255) / 256;
    int mmb = (nn + 15) / 16, aggb = (nn + 3) / 4;

    k_detect<<<1, 64, 0, stream>>>(ei, flag);
    k_zero<<<((int)zints + 255) / 256, 256, 0, stream>>>((int*)ws, (int)zints);
    k_count<<<eb, 256, 0, stream>>>(ei, cnt, flag, ne, nn);
    k_scan1<<<nb, 256, 0, stream>>>(cnt, rowp, bsum, dis, nn);
    k_scan2<<<1, 512, 0, stream>>>(bsum, nb);
    k_scan3<<<nb, 256, 0, stream>>>(rowp, bsum, nn);
    k_zero<<<nb, 256, 0, stream>>>(cnt, nn);         // cnt -> fill cursor
    k_fill<<<eb, 256, 0, stream>>>(ei, rowp, cnt, col, flag, ne, nn);

    k_mm<<<mmb, 256, (128 * 64 + 16 * 128) * 4, stream>>>(x, W1, A, nn, 128);
    k_agg<<<aggb, 256, 0, stream>>>(A, col, rowp, dis, b1, B, nn);
    k_mm<<<mmb, 256, (64 * 64 + 16 * 64) * 4, stream>>>(B, W2, A, nn, 64);
    k_agg<<<aggb, 256, 0, stream>>>(A, col, rowp, dis, b2, B, nn);
    k_mm<<<mmb, 256, (64 * 64 + 16 * 64) * 4, stream>>>(B, W3, A, nn, 64);
    k_agg<<<aggb, 256, 0, stream>>>(A, col, rowp, dis, b3, B, nn);

    k_pool<<<nb, 64, 0, stream>>>(B, bat, pool, flag, nn);
    k_mlp<<<1, 256, 0, stream>>>(pool, fW1, fb1, fW2, fb2, out);
}

// Round 24
// 976.402 us; speedup vs baseline: 1.2545x; 1.0209x over previous
//
#include <hip/hip_runtime.h>

__global__ void GraphCNN_48679159333670_kernel() {}

__device__ __forceinline__ int rdi(const int* p, int pos, int f64) {
    return f64 ? p[2 * pos] : p[pos];
}

__global__ void k_mark(float* out, float v) {
    int i = blockIdx.x * 64 + threadIdx.x;
    if (i < 1024) out[i] = v;
}
__global__ void k_detect(const int* ei, int* flag) {
    if (threadIdx.x == 0) {
        int nz = 0;
        for (int k = 0; k < 256; ++k) nz += (ei[2 * k + 1] != 0);
        flag[0] = (nz == 0);
    }
}
__global__ void k_zero(int* p, int n) {
    int i = blockIdx.x * 256 + threadIdx.x;
    if (i < n) p[i] = 0;
}
__global__ void k_count(const int* ei, int* cnt, const int* flag, int ne, int nn) {
    int i = blockIdx.x * 256 + threadIdx.x;
    if (i < ne) {
        unsigned d = (unsigned)rdi(ei, ne + i, flag[0]);
        if (d < (unsigned)nn) atomicAdd(&cnt[d], 1);
    }
}
// hierarchical scan stage 1: per-block inclusive scan; also dis = rsqrt(deg+1)
__global__ void k_scan1(const int* cnt, int* rowp, int* bsum, float* dis, int nn) {
    __shared__ int s[256];
    int t = threadIdx.x;
    int i = blockIdx.x * 256 + t;
    int v = (i < nn) ? cnt[i] : 0;
    if (i < nn) dis[i] = rsqrtf((float)v + 1.0f);
    s[t] = v;
    __syncthreads();
    for (int off = 1; off < 256; off <<= 1) {
        int u = (t >= off) ? s[t - off] : 0;
        __syncthreads();
        s[t] += u;
        __syncthreads();
    }
    if (i < nn) rowp[i + 1] = s[t];
    if (t == 255) bsum[blockIdx.x] = s[t];
}
__global__ void k_scan2(int* bsum, int nb) {
    __shared__ int s[512];
    int t = threadIdx.x;
    s[t] = (t < nb) ? bsum[t] : 0;
    __syncthreads();
    for (int off = 1; off < 512; off <<= 1) {
        int u = (t >= off) ? s[t - off] : 0;
        __syncthreads();
        s[t] += u;
        __syncthreads();
    }
    if (t < nb) bsum[t] = s[t];
}
__global__ void k_scan3(int* rowp, const int* bsum, int nn) {
    int i = blockIdx.x * 256 + threadIdx.x;
    if (i == 0) rowp[0] = 0;
    if (i < nn) {
        int b = i >> 8;
        if (b > 0) rowp[i + 1] += bsum[b - 1];
    }
}
__global__ void k_fill(const int* ei, const int* rowp, int* cur, int* col,
                       const int* flag, int ne, int nn) {
    int i = blockIdx.x * 256 + threadIdx.x;
    if (i < ne) {
        int f = flag[0];
        unsigned s = (unsigned)rdi(ei, i, f);
        unsigned d = (unsigned)rdi(ei, ne + i, f);
        if (s < (unsigned)nn && d < (unsigned)nn)
            col[rowp[d] + atomicAdd(&cur[d], 1)] = (int)s;
    }
}
// H = X @ W ; X:[nn,K] f32, W:[K,64] row-major; OUTPUT f16; 16 nodes/block
__global__ void k_mm(const float* X, const float* W, _Float16* H, int nn, int K) {
    extern __shared__ float sm[];
    float* Wl = sm;
    float* Xl = sm + K * 64;
    int t = threadIdx.x;
    for (int idx = t; idx < K * 64; idx += 256) Wl[idx] = W[idx];
    int n0 = blockIdx.x * 16;
    for (int idx = t; idx < 16 * K; idx += 256) {
        int node = n0 + idx / K;
        Xl[idx] = (node < nn) ? X[(size_t)node * K + idx % K] : 0.f;
    }
    __syncthreads();
    int q = t & 15, nl = t >> 4;
    float a0 = 0, a1 = 0, a2 = 0, a3 = 0;
    for (int k = 0; k < K; ++k) {
        float xv = Xl[nl * K + k];
        const float* w = &Wl[k * 64 + q * 4];
        a0 += xv * w[0]; a1 += xv * w[1]; a2 += xv * w[2]; a3 += xv * w[3];
    }
    int node = n0 + nl;
    if (node < nn) {
        _Float16* o = &H[(size_t)node * 64 + q * 4];
        o[0] = (_Float16)a0; o[1] = (_Float16)a1;
        o[2] = (_Float16)a2; o[3] = (_Float16)a3;
    }
}
// O = relu((sum_{s in N(i)} H[s]*dis[s] + H[i]*dis[i]) * dis[i] + b); 1 wave/node
// H is f16 (halves gather bytes), accumulate f32, O f32.
__global__ void k_agg(const _Float16* H, const int* col, const int* rowp,
                      const float* dis, const float* bias, float* O, int nn) {
    int i = blockIdx.x * 4 + (threadIdx.x >> 6);
    int lane = threadIdx.x & 63;
    if (i >= nn) return;
    int r0 = rowp[i], r1 = rowp[i + 1];
    float acc = 0.f;
    for (int j = r0; j < r1; ++j) {
        int s = col[j];
        acc += (float)H[(size_t)s * 64 + lane] * dis[s];
    }
    float di = dis[i];
    acc += (float)H[(size_t)i * 64 + lane] * di;
    O[(size_t)i * 64 + lane] = fmaxf(acc * di + bias[lane], 0.f);
}
// mean-pool over sorted batch ids; pool[g*64+c] sums, pool[4096+g] counts
__global__ void k_pool(const float* H, const int* batch, float* pool,
                       const int* flag, int nn) {
    int lane = threadIdx.x;
    int n0 = blockIdx.x * 256;
    if (n0 >= nn) return;
    int f = flag[0];
    int nend = (n0 + 256 < nn) ? n0 + 256 : nn;
    float acc = 0.f, cf = 0.f;
    int curg = rdi(batch, n0, f) & 63;
    for (int i = n0; i < nend; ++i) {
        int g = rdi(batch, i, f) & 63;
        if (g != curg) {
            atomicAdd(&pool[curg * 64 + lane], acc);
            if (lane == 0) atomicAdd(&pool[4096 + curg], cf);
            acc = 0.f; cf = 0.f; curg = g;
        }
        acc += H[(size_t)i * 64 + lane];
        cf += 1.f;
    }
    atomicAdd(&pool[curg * 64 + lane], acc);
    if (lane == 0) atomicAdd(&pool[4096 + curg], cf);
}
// MLP head + log_softmax; output f32
__global__ void k_mlp(const float* pool, const float* fW1, const float* fb1,
                      const float* fW2, const float* fb2, float* out) {
    __shared__ float w1[2048], w2[512], b1s[32], b2s[16], gm[4096];
    int t = threadIdx.x;
    for (int i = t; i < 2048; i += 256) w1[i] = fW1[i];
    for (int i = t; i < 512; i += 256) w2[i] = fW2[i];
    if (t < 32) b1s[t] = fb1[t];
    if (t < 16) b2s[t] = fb2[t];
    for (int i = t; i < 4096; i += 256) {
        float c = pool[4096 + (i >> 6)];
        gm[i] = pool[i] / ((c < 1.f) ? 1.f : c);
    }
    __syncthreads();
    if (t < 64) {
        float hid[32], lg[16];
        for (int j = 0; j < 32; ++j) {
            float s = b1s[j];
            for (int k = 0; k < 64; ++k) s += gm[t * 64 + k] * w1[k * 32 + j];
            hid[j] = fmaxf(s, 0.f);
        }
        float m = -1e30f;
        for (int j = 0; j < 16; ++j) {
            float s = b2s[j];
            for (int k = 0; k < 32; ++k) s += hid[k] * w2[k * 16 + j];
            lg[j] = s;
            m = fmaxf(m, s);
        }
        float se = 0.f;
        for (int j = 0; j < 16; ++j) se += expf(lg[j] - m);
        float lse = m + logf(se);
        for (int j = 0; j < 16; ++j) out[t * 16 + j] = lg[j] - lse;
    }
}

extern "C" void kernel_launch(void* const* d_in, const int* in_sizes, int n_in,
                              void* d_out, int out_size, void* d_ws, size_t ws_size,
                              hipStream_t stream) {
    (void)in_sizes; (void)n_in; (void)out_size;
    const int nn = 100000, ne = 1600000;
    const float* x   = (const float*)d_in[0];
    const int*   ei  = (const int*)d_in[1];
    const int*   bat = (const int*)d_in[2];
    const float* W1  = (const float*)d_in[3];
    const float* b1  = (const float*)d_in[4];
    const float* W2  = (const float*)d_in[5];
    const float* b2  = (const float*)d_in[6];
    const float* W3  = (const float*)d_in[7];
    const float* b3  = (const float*)d_in[8];
    const float* fW1 = (const float*)d_in[9];
    const float* fb1 = (const float*)d_in[10];
    const float* fW2 = (const float*)d_in[11];
    const float* fb2 = (const float*)d_in[12];
    float* out = (float*)d_out;   // f32 output (r21: out_nbytes==4096)

    char* ws = (char*)d_ws;
    size_t o = 0;
    int*      cnt  = (int*)(ws + o);      o += 400128;     // nn*4
    float*    pool = (float*)(ws + o);    o += 16896;      // 64*64 + 64
    size_t zints = o / 4;                                  // cnt+pool zero region
    int*      rowp = (int*)(ws + o);      o += 400384;     // (nn+1)*4
    int*      bsum = (int*)(ws + o);      o += 2048;
    float*    dis  = (float*)(ws + o);    o += 400128;
    int*      flag = (int*)(ws + o);      o += 256;
    int*      col  = (int*)(ws + o);      o += 6400000;    // ne*4
    _Float16* A    = (_Float16*)(ws + o); o += 12800000;   // nn*64*2 (f16 gather buf)
    float*    B    = (float*)(ws + o);    o += 25600000;   // nn*64*4
    if (ws_size < o) {
        k_mark<<<16, 64, 0, stream>>>(out, 150.0f);
        return;
    }

    int eb = (ne + 255) / 256, nb = (nn + 255) / 256;
    int mmb = (nn + 15) / 16, aggb = (nn + 3) / 4;

    k_detect<<<1, 64, 0, stream>>>(ei, flag);
    k_zero<<<((int)zints + 255) / 256, 256, 0, stream>>>((int*)ws, (int)zints);
    k_count<<<eb, 256, 0, stream>>>(ei, cnt, flag, ne, nn);
    k_scan1<<<nb, 256, 0, stream>>>(cnt, rowp, bsum, dis, nn);
    k_scan2<<<1, 512, 0, stream>>>(bsum, nb);
    k_scan3<<<nb, 256, 0, stream>>>(rowp, bsum, nn);
    k_zero<<<nb, 256, 0, stream>>>(cnt, nn);         // cnt -> fill cursor
    k_fill<<<eb, 256, 0, stream>>>(ei, rowp, cnt, col, flag, ne, nn);

    // layer 1: x(f32) -> A(f16) -> B(f32)
    k_mm<<<mmb, 256, (128 * 64 + 16 * 128) * 4, stream>>>(x, W1, A, nn, 128);
    k_agg<<<aggb, 256, 0, stream>>>(A, col, rowp, dis, b1, B, nn);
    // layer 2: B(f32) -> A(f16) -> B(f32)
    k_mm<<<mmb, 256, (64 * 64 + 16 * 64) * 4, stream>>>(B, W2, A, nn, 64);
    k_agg<<<aggb, 256, 0, stream>>>(A, col, rowp, dis, b2, B, nn);
    // layer 3
    k_mm<<<mmb, 256, (64 * 64 + 16 * 64) * 4, stream>>>(B, W3, A, nn, 64);
    k_agg<<<aggb, 256, 0, stream>>>(A, col, rowp, dis, b3, B, nn);

    k_pool<<<nb, 64, 0, stream>>>(B, bat, pool, flag, nn);
    k_mlp<<<1, 256, 0, stream>>>(pool, fW1, fb1, fW2, fb2, out);
}

// Round 25
// 755.819 us; speedup vs baseline: 1.6207x; 1.2918x over previous
//
#include <hip/hip_runtime.h>

__global__ void GraphCNN_48679159333670_kernel() {}

__device__ __forceinline__ int rdi(const int* p, int pos, int f64) {
    return f64 ? p[2 * pos] : p[pos];
}

__global__ void k_mark(float* out, float v) {
    int i = blockIdx.x * 64 + threadIdx.x;
    if (i < 1024) out[i] = v;
}
__global__ void k_detect(const int* ei, int* flag) {
    if (threadIdx.x == 0) {
        int nz = 0;
        for (int k = 0; k < 256; ++k) nz += (ei[2 * k + 1] != 0);
        flag[0] = (nz == 0);
    }
}
__global__ void k_zero(int* p, int n) {
    int i = blockIdx.x * 256 + threadIdx.x;
    if (i < n) p[i] = 0;
}
__global__ void k_count(const int* ei, int* cnt, const int* flag, int ne, int nn) {
    int i = blockIdx.x * 256 + threadIdx.x;
    if (i < ne) {
        unsigned d = (unsigned)rdi(ei, ne + i, flag[0]);
        if (d < (unsigned)nn) atomicAdd(&cnt[d], 1);
    }
}
// hierarchical scan stage 1: per-block inclusive scan; also dis = rsqrt(deg+1)
__global__ void k_scan1(const int* cnt, int* rowp, int* bsum, float* dis, int nn) {
    __shared__ int s[256];
    int t = threadIdx.x;
    int i = blockIdx.x * 256 + t;
    int v = (i < nn) ? cnt[i] : 0;
    if (i < nn) dis[i] = rsqrtf((float)v + 1.0f);
    s[t] = v;
    __syncthreads();
    for (int off = 1; off < 256; off <<= 1) {
        int u = (t >= off) ? s[t - off] : 0;
        __syncthreads();
        s[t] += u;
        __syncthreads();
    }
    if (i < nn) rowp[i + 1] = s[t];
    if (t == 255) bsum[blockIdx.x] = s[t];
}
__global__ void k_scan2(int* bsum, int nb) {
    __shared__ int s[512];
    int t = threadIdx.x;
    s[t] = (t < nb) ? bsum[t] : 0;
    __syncthreads();
    for (int off = 1; off < 512; off <<= 1) {
        int u = (t >= off) ? s[t - off] : 0;
        __syncthreads();
        s[t] += u;
        __syncthreads();
    }
    if (t < nb) bsum[t] = s[t];
}
__global__ void k_scan3(int* rowp, const int* bsum, int nn) {
    int i = blockIdx.x * 256 + threadIdx.x;
    if (i == 0) rowp[0] = 0;
    if (i < nn) {
        int b = i >> 8;
        if (b > 0) rowp[i + 1] += bsum[b - 1];
    }
}
__global__ void k_fill(const int* ei, const int* rowp, int* cur, int* col,
                       const int* flag, int ne, int nn) {
    int i = blockIdx.x * 256 + threadIdx.x;
    if (i < ne) {
        int f = flag[0];
        unsigned s = (unsigned)rdi(ei, i, f);
        unsigned d = (unsigned)rdi(ei, ne + i, f);
        if (s < (unsigned)nn && d < (unsigned)nn)
            col[rowp[d] + atomicAdd(&cur[d], 1)] = (int)s;
    }
}
// H = X @ W ; X:[nn,K] f32, W:[K,64] row-major; OUTPUT f16; 16 nodes/block
__global__ void k_mm(const float* X, const float* W, _Float16* H, int nn, int K) {
    extern __shared__ float sm[];
    float* Wl = sm;
    float* Xl = sm + K * 64;
    int t = threadIdx.x;
    for (int idx = t; idx < K * 64; idx += 256) Wl[idx] = W[idx];
    int n0 = blockIdx.x * 16;
    for (int idx = t; idx < 16 * K; idx += 256) {
        int node = n0 + idx / K;
        Xl[idx] = (node < nn) ? X[(size_t)node * K + idx % K] : 0.f;
    }
    __syncthreads();
    int q = t & 15, nl = t >> 4;
    float a0 = 0, a1 = 0, a2 = 0, a3 = 0;
    for (int k = 0; k < K; ++k) {
        float xv = Xl[nl * K + k];
        const float* w = &Wl[k * 64 + q * 4];
        a0 += xv * w[0]; a1 += xv * w[1]; a2 += xv * w[2]; a3 += xv * w[3];
    }
    int node = n0 + nl;
    if (node < nn) {
        _Float16* o = &H[(size_t)node * 64 + q * 4];
        o[0] = (_Float16)a0; o[1] = (_Float16)a1;
        o[2] = (_Float16)a2; o[3] = (_Float16)a3;
    }
}
// O = relu((sum_{s in N(i)} H[s]*dis[s] + H[i]*dis[i]) * dis[i] + b); 1 wave/node.
// 4x edge unroll: 4 independent H-row gathers in flight per wave (MLP for latency).
__global__ void k_agg(const _Float16* H, const int* col, const int* rowp,
                      const float* dis, const float* bias, float* O, int nn) {
    int i = blockIdx.x * 4 + (threadIdx.x >> 6);
    int lane = threadIdx.x & 63;
    if (i >= nn) return;
    int r0 = rowp[i], r1 = rowp[i + 1];
    float acc = 0.f;
    int j = r0;
    for (; j + 4 <= r1; j += 4) {
        int s0 = col[j + 0];
        int s1 = col[j + 1];
        int s2 = col[j + 2];
        int s3 = col[j + 3];
        float h0 = (float)H[(size_t)s0 * 64 + lane];
        float h1 = (float)H[(size_t)s1 * 64 + lane];
        float h2 = (float)H[(size_t)s2 * 64 + lane];
        float h3 = (float)H[(size_t)s3 * 64 + lane];
        float d0 = dis[s0];
        float d1 = dis[s1];
        float d2 = dis[s2];
        float d3 = dis[s3];
        acc += h0 * d0;
        acc += h1 * d1;
        acc += h2 * d2;
        acc += h3 * d3;
    }
    for (; j < r1; ++j) {
        int s = col[j];
        acc += (float)H[(size_t)s * 64 + lane] * dis[s];
    }
    float di = dis[i];
    acc += (float)H[(size_t)i * 64 + lane] * di;
    O[(size_t)i * 64 + lane] = fmaxf(acc * di + bias[lane], 0.f);
}
// mean-pool over sorted batch ids; pool[g*64+c] sums, pool[4096+g] counts
__global__ void k_pool(const float* H, const int* batch, float* pool,
                       const int* flag, int nn) {
    int lane = threadIdx.x;
    int n0 = blockIdx.x * 256;
    if (n0 >= nn) return;
    int f = flag[0];
    int nend = (n0 + 256 < nn) ? n0 + 256 : nn;
    float acc = 0.f, cf = 0.f;
    int curg = rdi(batch, n0, f) & 63;
    for (int i = n0; i < nend; ++i) {
        int g = rdi(batch, i, f) & 63;
        if (g != curg) {
            atomicAdd(&pool[curg * 64 + lane], acc);
            if (lane == 0) atomicAdd(&pool[4096 + curg], cf);
            acc = 0.f; cf = 0.f; curg = g;
        }
        acc += H[(size_t)i * 64 + lane];
        cf += 1.f;
    }
    atomicAdd(&pool[curg * 64 + lane], acc);
    if (lane == 0) atomicAdd(&pool[4096 + curg], cf);
}
// MLP head + log_softmax; output f32
__global__ void k_mlp(const float* pool, const float* fW1, const float* fb1,
                      const float* fW2, const float* fb2, float* out) {
    __shared__ float w1[2048], w2[512], b1s[32], b2s[16], gm[4096];
    int t = threadIdx.x;
    for (int i = t; i < 2048; i += 256) w1[i] = fW1[i];
    for (int i = t; i < 512; i += 256) w2[i] = fW2[i];
    if (t < 32) b1s[t] = fb1[t];
    if (t < 16) b2s[t] = fb2[t];
    for (int i = t; i < 4096; i += 256) {
        float c = pool[4096 + (i >> 6)];
        gm[i] = pool[i] / ((c < 1.f) ? 1.f : c);
    }
    __syncthreads();
    if (t < 64) {
        float hid[32], lg[16];
        for (int j = 0; j < 32; ++j) {
            float s = b1s[j];
            for (int k = 0; k < 64; ++k) s += gm[t * 64 + k] * w1[k * 32 + j];
            hid[j] = fmaxf(s, 0.f);
        }
        float m = -1e30f;
        for (int j = 0; j < 16; ++j) {
            float s = b2s[j];
            for (int k = 0; k < 32; ++k) s += hid[k] * w2[k * 16 + j];
            lg[j] = s;
            m = fmaxf(m, s);
        }
        float se = 0.f;
        for (int j = 0; j < 16; ++j) se += expf(lg[j] - m);
        float lse = m + logf(se);
        for (int j = 0; j < 16; ++j) out[t * 16 + j] = lg[j] - lse;
    }
}

extern "C" void kernel_launch(void* const* d_in, const int* in_sizes, int n_in,
                              void* d_out, int out_size, void* d_ws, size_t ws_size,
                              hipStream_t stream) {
    (void)in_sizes; (void)n_in; (void)out_size;
    const int nn = 100000, ne = 1600000;
    const float* x   = (const float*)d_in[0];
    const int*   ei  = (const int*)d_in[1];
    const int*   bat = (const int*)d_in[2];
    const float* W1  = (const float*)d_in[3];
    const float* b1  = (const float*)d_in[4];
    const float* W2  = (const float*)d_in[5];
    const float* b2  = (const float*)d_in[6];
    const float* W3  = (const float*)d_in[7];
    const float* b3  = (const float*)d_in[8];
    const float* fW1 = (const float*)d_in[9];
    const float* fb1 = (const float*)d_in[10];
    const float* fW2 = (const float*)d_in[11];
    const float* fb2 = (const float*)d_in[12];
    float* out = (float*)d_out;   // f32 output (r21: out_nbytes==4096)

    char* ws = (char*)d_ws;
    size_t o = 0;
    int*      cnt  = (int*)(ws + o);      o += 400128;     // nn*4
    float*    pool = (float*)(ws + o);    o += 16896;      // 64*64 + 64
    size_t zints = o / 4;                                  // cnt+pool zero region
    int*      rowp = (int*)(ws + o);      o += 400384;     // (nn+1)*4
    int*      bsum = (int*)(ws + o);      o += 2048;
    float*    dis  = (float*)(ws + o);    o += 400128;
    int*      flag = (int*)(ws + o);      o += 256;
    int*      col  = (int*)(ws + o);      o += 6400000;    // ne*4
    _Float16* A    = (_Float16*)(ws + o); o += 12800000;   // nn*64*2 (f16 gather buf)
    float*    B    = (float*)(ws + o);    o += 25600000;   // nn*64*4
    if (ws_size < o) {
        k_mark<<<16, 64, 0, stream>>>(out, 150.0f);
        return;
    }

    int eb = (ne + 255) / 256, nb = (nn + 255) / 256;
    int mmb = (nn + 15) / 16, aggb = (nn + 3) / 4;

    k_detect<<<1, 64, 0, stream>>>(ei, flag);
    k_zero<<<((int)zints + 255) / 256, 256, 0, stream>>>((int*)ws, (int)zints);
    k_count<<<eb, 256, 0, stream>>>(ei, cnt, flag, ne, nn);
    k_scan1<<<nb, 256, 0, stream>>>(cnt, rowp, bsum, dis, nn);
    k_scan2<<<1, 512, 0, stream>>>(bsum, nb);
    k_scan3<<<nb, 256, 0, stream>>>(rowp, bsum, nn);
    k_zero<<<nb, 256, 0, stream>>>(cnt, nn);         // cnt -> fill cursor
    k_fill<<<eb, 256, 0, stream>>>(ei, rowp, cnt, col, flag, ne, nn);

    // layer 1: x(f32) -> A(f16) -> B(f32)
    k_mm<<<mmb, 256, (128 * 64 + 16 * 128) * 4, stream>>>(x, W1, A, nn, 128);
    k_agg<<<aggb, 256, 0, stream>>>(A, col, rowp, dis, b1, B, nn);
    // layer 2: B(f32) -> A(f16) -> B(f32)
    k_mm<<<mmb, 256, (64 * 64 + 16 * 64) * 4, stream>>>(B, W2, A, nn, 64);
    k_agg<<<aggb, 256, 0, stream>>>(A, col, rowp, dis, b2, B, nn);
    // layer 3
    k_mm<<<mmb, 256, (64 * 64 + 16 * 64) * 4, stream>>>(B, W3, A, nn, 64);
    k_agg<<<aggb, 256, 0, stream>>>(A, col, rowp, dis, b3, B, nn);

    k_pool<<<nb, 64, 0, stream>>>(B, bat, pool, flag, nn);
    k_mlp<<<1, 256, 0, stream>>>(pool, fW1, fb1, fW2, fb2, out);
}

// Round 26
// 725.968 us; speedup vs baseline: 1.6873x; 1.0411x over previous
//
#include <hip/hip_runtime.h>

__global__ void GraphCNN_48679159333670_kernel() {}

__device__ __forceinline__ int rdi(const int* p, int pos, int f64) {
    return f64 ? p[2 * pos] : p[pos];
}

__global__ void k_mark(float* out, float v) {
    int i = blockIdx.x * 64 + threadIdx.x;
    if (i < 1024) out[i] = v;
}
__global__ void k_detect(const int* ei, int* flag) {
    if (threadIdx.x == 0) {
        int nz = 0;
        for (int k = 0; k < 256; ++k) nz += (ei[2 * k + 1] != 0);
        flag[0] = (nz == 0);
    }
}
__global__ void k_zero(int* p, int n) {
    int i = blockIdx.x * 256 + threadIdx.x;
    if (i < n) p[i] = 0;
}
__global__ void k_count(const int* ei, int* cnt, const int* flag, int ne, int nn) {
    int i = blockIdx.x * 256 + threadIdx.x;
    if (i < ne) {
        unsigned d = (unsigned)rdi(ei, ne + i, flag[0]);
        if (d < (unsigned)nn) atomicAdd(&cnt[d], 1);
    }
}
// hierarchical scan stage 1: per-block inclusive scan; also dis = rsqrt(deg+1)
__global__ void k_scan1(const int* cnt, int* rowp, int* bsum, float* dis, int nn) {
    __shared__ int s[256];
    int t = threadIdx.x;
    int i = blockIdx.x * 256 + t;
    int v = (i < nn) ? cnt[i] : 0;
    if (i < nn) dis[i] = rsqrtf((float)v + 1.0f);
    s[t] = v;
    __syncthreads();
    for (int off = 1; off < 256; off <<= 1) {
        int u = (t >= off) ? s[t - off] : 0;
        __syncthreads();
        s[t] += u;
        __syncthreads();
    }
    if (i < nn) rowp[i + 1] = s[t];
    if (t == 255) bsum[blockIdx.x] = s[t];
}
__global__ void k_scan2(int* bsum, int nb) {
    __shared__ int s[512];
    int t = threadIdx.x;
    s[t] = (t < nb) ? bsum[t] : 0;
    __syncthreads();
    for (int off = 1; off < 512; off <<= 1) {
        int u = (t >= off) ? s[t - off] : 0;
        __syncthreads();
        s[t] += u;
        __syncthreads();
    }
    if (t < nb) bsum[t] = s[t];
}
__global__ void k_scan3(int* rowp, const int* bsum, int nn) {
    int i = blockIdx.x * 256 + threadIdx.x;
    if (i == 0) rowp[0] = 0;
    if (i < nn) {
        int b = i >> 8;
        if (b > 0) rowp[i + 1] += bsum[b - 1];
    }
}
__global__ void k_fill(const int* ei, const int* rowp, int* cur, int* col,
                       const int* flag, int ne, int nn) {
    int i = blockIdx.x * 256 + threadIdx.x;
    if (i < ne) {
        int f = flag[0];
        unsigned s = (unsigned)rdi(ei, i, f);
        unsigned d = (unsigned)rdi(ei, ne + i, f);
        if (s < (unsigned)nn && d < (unsigned)nn)
            col[rowp[d] + atomicAdd(&cur[d], 1)] = (int)s;
    }
}
// H = X @ W ; X:[nn,K] f32, W:[K,64] row-major; OUTPUT f16; 16 nodes/block.
// Xl leading dim padded to K+1: (K+1)%32==1 so the 4 nl-rows a wave reads land
// in distinct banks (K%32==0 put them all in one bank: 3.2e7 conflicts, r25).
__global__ void k_mm(const float* X, const float* W, _Float16* H, int nn, int K) {
    extern __shared__ float sm[];
    float* Wl = sm;                 // K*64
    float* Xl = sm + K * 64;        // 16*(K+1)
    const int KS = K + 1;
    int t = threadIdx.x;
    for (int idx = t; idx < K * 64; idx += 256) Wl[idx] = W[idx];
    int n0 = blockIdx.x * 16;
    for (int idx = t; idx < 16 * K; idx += 256) {
        int node = n0 + idx / K;
        int k = idx % K;
        Xl[(idx / K) * KS + k] = (node < nn) ? X[(size_t)node * K + k] : 0.f;
    }
    __syncthreads();
    int q = t & 15, nl = t >> 4;
    float a0 = 0, a1 = 0, a2 = 0, a3 = 0;
    const float* xr = &Xl[nl * KS];
    for (int k = 0; k < K; ++k) {
        float xv = xr[k];
        const float* w = &Wl[k * 64 + q * 4];
        a0 += xv * w[0]; a1 += xv * w[1]; a2 += xv * w[2]; a3 += xv * w[3];
    }
    int node = n0 + nl;
    if (node < nn) {
        _Float16* o = &H[(size_t)node * 64 + q * 4];
        o[0] = (_Float16)a0; o[1] = (_Float16)a1;
        o[2] = (_Float16)a2; o[3] = (_Float16)a3;
    }
}
// O = relu((sum_{s in N(i)} H[s]*dis[s] + H[i]*dis[i]) * dis[i] + b); 1 wave/node.
// 4x edge unroll keeps 4 independent gathers in flight (r25: 146 -> ~60 us).
__global__ void k_agg(const _Float16* H, const int* col, const int* rowp,
                      const float* dis, const float* bias, float* O, int nn) {
    int i = blockIdx.x * 4 + (threadIdx.x >> 6);
    int lane = threadIdx.x & 63;
    if (i >= nn) return;
    int r0 = rowp[i], r1 = rowp[i + 1];
    float acc = 0.f;
    int j = r0;
    for (; j + 4 <= r1; j += 4) {
        int s0 = col[j + 0];
        int s1 = col[j + 1];
        int s2 = col[j + 2];
        int s3 = col[j + 3];
        float h0 = (float)H[(size_t)s0 * 64 + lane];
        float h1 = (float)H[(size_t)s1 * 64 + lane];
        float h2 = (float)H[(size_t)s2 * 64 + lane];
        float h3 = (float)H[(size_t)s3 * 64 + lane];
        float d0 = dis[s0];
        float d1 = dis[s1];
        float d2 = dis[s2];
        float d3 = dis[s3];
        acc += h0 * d0;
        acc += h1 * d1;
        acc += h2 * d2;
        acc += h3 * d3;
    }
    for (; j < r1; ++j) {
        int s = col[j];
        acc += (float)H[(size_t)s * 64 + lane] * dis[s];
    }
    float di = dis[i];
    acc += (float)H[(size_t)i * 64 + lane] * di;
    O[(size_t)i * 64 + lane] = fmaxf(acc * di + bias[lane], 0.f);
}
// mean-pool over sorted batch ids; pool[g*64+c] sums, pool[4096+g] counts
__global__ void k_pool(const float* H, const int* batch, float* pool,
                       const int* flag, int nn) {
    int lane = threadIdx.x;
    int n0 = blockIdx.x * 256;
    if (n0 >= nn) return;
    int f = flag[0];
    int nend = (n0 + 256 < nn) ? n0 + 256 : nn;
    float acc = 0.f, cf = 0.f;
    int curg = rdi(batch, n0, f) & 63;
    for (int i = n0; i < nend; ++i) {
        int g = rdi(batch, i, f) & 63;
        if (g != curg) {
            atomicAdd(&pool[curg * 64 + lane], acc);
            if (lane == 0) atomicAdd(&pool[4096 + curg], cf);
            acc = 0.f; cf = 0.f; curg = g;
        }
        acc += H[(size_t)i * 64 + lane];
        cf += 1.f;
    }
    atomicAdd(&pool[curg * 64 + lane], acc);
    if (lane == 0) atomicAdd(&pool[4096 + curg], cf);
}
// MLP head + log_softmax; output f32
__global__ void k_mlp(const float* pool, const float* fW1, const float* fb1,
                      const float* fW2, const float* fb2, float* out) {
    __shared__ float w1[2048], w2[512], b1s[32], b2s[16], gm[4096];
    int t = threadIdx.x;
    for (int i = t; i < 2048; i += 256) w1[i] = fW1[i];
    for (int i = t; i < 512; i += 256) w2[i] = fW2[i];
    if (t < 32) b1s[t] = fb1[t];
    if (t < 16) b2s[t] = fb2[t];
    for (int i = t; i < 4096; i += 256) {
        float c = pool[4096 + (i >> 6)];
        gm[i] = pool[i] / ((c < 1.f) ? 1.f : c);
    }
    __syncthreads();
    if (t < 64) {
        float hid[32], lg[16];
        for (int j = 0; j < 32; ++j) {
            float s = b1s[j];
            for (int k = 0; k < 64; ++k) s += gm[t * 64 + k] * w1[k * 32 + j];
            hid[j] = fmaxf(s, 0.f);
        }
        float m = -1e30f;
        for (int j = 0; j < 16; ++j) {
            float s = b2s[j];
            for (int k = 0; k < 32; ++k) s += hid[k] * w2[k * 16 + j];
            lg[j] = s;
            m = fmaxf(m, s);
        }
        float se = 0.f;
        for (int j = 0; j < 16; ++j) se += expf(lg[j] - m);
        float lse = m + logf(se);
        for (int j = 0; j < 16; ++j) out[t * 16 + j] = lg[j] - lse;
    }
}

extern "C" void kernel_launch(void* const* d_in, const int* in_sizes, int n_in,
                              void* d_out, int out_size, void* d_ws, size_t ws_size,
                              hipStream_t stream) {
    (void)in_sizes; (void)n_in; (void)out_size;
    const int nn = 100000, ne = 1600000;
    const float* x   = (const float*)d_in[0];
    const int*   ei  = (const int*)d_in[1];
    const int*   bat = (const int*)d_in[2];
    const float* W1  = (const float*)d_in[3];
    const float* b1  = (const float*)d_in[4];
    const float* W2  = (const float*)d_in[5];
    const float* b2  = (const float*)d_in[6];
    const float* W3  = (const float*)d_in[7];
    const float* b3  = (const float*)d_in[8];
    const float* fW1 = (const float*)d_in[9];
    const float* fb1 = (const float*)d_in[10];
    const float* fW2 = (const float*)d_in[11];
    const float* fb2 = (const float*)d_in[12];
    float* out = (float*)d_out;   // f32 output (r21: out_nbytes==4096)

    char* ws = (char*)d_ws;
    size_t o = 0;
    int*      cnt  = (int*)(ws + o);      o += 400128;     // nn*4
    float*    pool = (float*)(ws + o);    o += 16896;      // 64*64 + 64
    size_t zints = o / 4;                                  // cnt+pool zero region
    int*      rowp = (int*)(ws + o);      o += 400384;     // (nn+1)*4
    int*      bsum = (int*)(ws + o);      o += 2048;
    float*    dis  = (float*)(ws + o);    o += 400128;
    int*      flag = (int*)(ws + o);      o += 256;
    int*      col  = (int*)(ws + o);      o += 6400000;    // ne*4
    _Float16* A    = (_Float16*)(ws + o); o += 12800000;   // nn*64*2 (f16 gather buf)
    float*    B    = (float*)(ws + o);    o += 25600000;   // nn*64*4
    if (ws_size < o) {
        k_mark<<<16, 64, 0, stream>>>(out, 150.0f);
        return;
    }

    int eb = (ne + 255) / 256, nb = (nn + 255) / 256;
    int mmb = (nn + 15) / 16, aggb = (nn + 3) / 4;

    k_detect<<<1, 64, 0, stream>>>(ei, flag);
    k_zero<<<((int)zints + 255) / 256, 256, 0, stream>>>((int*)ws, (int)zints);
    k_count<<<eb, 256, 0, stream>>>(ei, cnt, flag, ne, nn);
    k_scan1<<<nb, 256, 0, stream>>>(cnt, rowp, bsum, dis, nn);
    k_scan2<<<1, 512, 0, stream>>>(bsum, nb);
    k_scan3<<<nb, 256, 0, stream>>>(rowp, bsum, nn);
    k_zero<<<nb, 256, 0, stream>>>(cnt, nn);         // cnt -> fill cursor
    k_fill<<<eb, 256, 0, stream>>>(ei, rowp, cnt, col, flag, ne, nn);

    // layer 1: x(f32) -> A(f16) -> B(f32)
    k_mm<<<mmb, 256, (128 * 64 + 16 * 129) * 4, stream>>>(x, W1, A, nn, 128);
    k_agg<<<aggb, 256, 0, stream>>>(A, col, rowp, dis, b1, B, nn);
    // layer 2: B(f32) -> A(f16) -> B(f32)
    k_mm<<<mmb, 256, (64 * 64 + 16 * 65) * 4, stream>>>(B, W2, A, nn, 64);
    k_agg<<<aggb, 256, 0, stream>>>(A, col, rowp, dis, b2, B, nn);
    // layer 3
    k_mm<<<mmb, 256, (64 * 64 + 16 * 65) * 4, stream>>>(B, W3, A, nn, 64);
    k_agg<<<aggb, 256, 0, stream>>>(A, col, rowp, dis, b3, B, nn);

    k_pool<<<nb, 64, 0, stream>>>(B, bat, pool, flag, nn);
    k_mlp<<<1, 256, 0, stream>>>(pool, fW1, fb1, fW2, fb2, out);
}

// Round 27
// 576.184 us; speedup vs baseline: 2.1259x; 1.2600x over previous
//
#include <hip/hip_runtime.h>

typedef _Float16 f16x8 __attribute__((ext_vector_type(8)));
typedef float f32x4 __attribute__((ext_vector_type(4)));

__global__ void GraphCNN_48679159333670_kernel() {}

__device__ __forceinline__ int rdi(const int* p, int pos, int f64) {
    return f64 ? p[2 * pos] : p[pos];
}

__global__ void k_mark(float* out, float v) {
    int i = blockIdx.x * 64 + threadIdx.x;
    if (i < 1024) out[i] = v;
}
__global__ void k_detect(const int* ei, int* flag) {
    if (threadIdx.x == 0) {
        int nz = 0;
        for (int k = 0; k < 256; ++k) nz += (ei[2 * k + 1] != 0);
        flag[0] = (nz == 0);
    }
}
__global__ void k_zero(int* p, int n) {
    int i = blockIdx.x * 256 + threadIdx.x;
    if (i < n) p[i] = 0;
}
__global__ void k_count(const int* ei, int* cnt, const int* flag, int ne, int nn) {
    int i = blockIdx.x * 256 + threadIdx.x;
    if (i < ne) {
        unsigned d = (unsigned)rdi(ei, ne + i, flag[0]);
        if (d < (unsigned)nn) atomicAdd(&cnt[d], 1);
    }
}
__global__ void k_scan1(const int* cnt, int* rowp, int* bsum, float* dis, int nn) {
    __shared__ int s[256];
    int t = threadIdx.x;
    int i = blockIdx.x * 256 + t;
    int v = (i < nn) ? cnt[i] : 0;
    if (i < nn) dis[i] = rsqrtf((float)v + 1.0f);
    s[t] = v;
    __syncthreads();
    for (int off = 1; off < 256; off <<= 1) {
        int u = (t >= off) ? s[t - off] : 0;
        __syncthreads();
        s[t] += u;
        __syncthreads();
    }
    if (i < nn) rowp[i + 1] = s[t];
    if (t == 255) bsum[blockIdx.x] = s[t];
}
__global__ void k_scan2(int* bsum, int nb) {
    __shared__ int s[512];
    int t = threadIdx.x;
    s[t] = (t < nb) ? bsum[t] : 0;
    __syncthreads();
    for (int off = 1; off < 512; off <<= 1) {
        int u = (t >= off) ? s[t - off] : 0;
        __syncthreads();
        s[t] += u;
        __syncthreads();
    }
    if (t < nb) bsum[t] = s[t];
}
__global__ void k_scan3(int* rowp, const int* bsum, int nn) {
    int i = blockIdx.x * 256 + threadIdx.x;
    if (i == 0) rowp[0] = 0;
    if (i < nn) {
        int b = i >> 8;
        if (b > 0) rowp[i + 1] += bsum[b - 1];
    }
}
__global__ void k_fill(const int* ei, const int* rowp, int* cur, int* col,
                       const int* flag, int ne, int nn) {
    int i = blockIdx.x * 256 + threadIdx.x;
    if (i < ne) {
        int f = flag[0];
        unsigned s = (unsigned)rdi(ei, i, f);
        unsigned d = (unsigned)rdi(ei, ne + i, f);
        if (s < (unsigned)nn && d < (unsigned)nn)
            col[rowp[d] + atomicAdd(&cur[d], 1)] = (int)s;
    }
}
// pack W[K][64] f32 into MFMA B-fragment order, f16:
// Wp[((kk*4 + w)*64 + lane)*8 + i] = W[kk*32 + (lane>>4)*8 + i][w*16 + (lane&15)]
__global__ void k_pack(const float* W, _Float16* Wp, int K) {
    int total = (K / 32) * 2048;
    int idx = blockIdx.x * 256 + threadIdx.x;
    if (idx < total) {
        int i = idx & 7;
        int lane = (idx >> 3) & 63;
        int w = (idx >> 9) & 3;
        int kk = idx >> 11;
        int k = kk * 32 + (lane >> 4) * 8 + i;
        int n = w * 16 + (lane & 15);
        Wp[idx] = (_Float16)W[k * 64 + n];
    }
}
// H = X @ W via mfma_f32_16x16x32_f16. Block = 4 waves = 16 nodes x 64 ch.
// A (X-rows) straight from global (f32 -> f16 in reg); B from packed Wp.
// Fragment maps: A[m=l&15][k=(l>>4)*8+i]; B[k=(l>>4)*8+i][n=l&15];
// D[m=(l>>4)*4+r][n=l&15] (C/D verified m89/m91, dtype-independent).
__global__ void k_mm_mfma(const float* X, const _Float16* Wp, _Float16* H, int K) {
    int l = threadIdx.x & 63;
    int w = threadIdx.x >> 6;
    int n0 = blockIdx.x * 16;          // nn % 16 == 0: no guards
    int am = l & 15;                   // A row (node within tile)
    int kg = l >> 4;                   // k-group
    const float* xrow = X + (size_t)(n0 + am) * K + kg * 8;
    f32x4 acc = {0.f, 0.f, 0.f, 0.f};
    for (int kk = 0; kk < K / 32; ++kk) {
        const float4* xp = (const float4*)(xrow + kk * 32);
        float4 xa = xp[0];
        float4 xb = xp[1];
        f16x8 a = { (_Float16)xa.x, (_Float16)xa.y, (_Float16)xa.z, (_Float16)xa.w,
                    (_Float16)xb.x, (_Float16)xb.y, (_Float16)xb.z, (_Float16)xb.w };
        f16x8 b = *(const f16x8*)(Wp + ((size_t)(kk * 4 + w) * 64 + l) * 8);
        acc = __builtin_amdgcn_mfma_f32_16x16x32_f16(a, b, acc, 0, 0, 0);
    }
    int dn = w * 16 + (l & 15);        // channel
    int dm0 = (l >> 4) * 4;            // node row base
#pragma unroll
    for (int r = 0; r < 4; ++r)
        H[(size_t)(n0 + dm0 + r) * 64 + dn] = (_Float16)acc[r];
}
// O = relu((sum_{s in N(i)} H[s]*dis[s] + H[i]*dis[i]) * dis[i] + b); 1 wave/node.
// 4x edge unroll keeps 4 independent gathers in flight.
__global__ void k_agg(const _Float16* H, const int* col, const int* rowp,
                      const float* dis, const float* bias, float* O, int nn) {
    int i = blockIdx.x * 4 + (threadIdx.x >> 6);
    int lane = threadIdx.x & 63;
    if (i >= nn) return;
    int r0 = rowp[i], r1 = rowp[i + 1];
    float acc = 0.f;
    int j = r0;
    for (; j + 4 <= r1; j += 4) {
        int s0 = col[j + 0];
        int s1 = col[j + 1];
        int s2 = col[j + 2];
        int s3 = col[j + 3];
        float h0 = (float)H[(size_t)s0 * 64 + lane];
        float h1 = (float)H[(size_t)s1 * 64 + lane];
        float h2 = (float)H[(size_t)s2 * 64 + lane];
        float h3 = (float)H[(size_t)s3 * 64 + lane];
        float d0 = dis[s0];
        float d1 = dis[s1];
        float d2 = dis[s2];
        float d3 = dis[s3];
        acc += h0 * d0;
        acc += h1 * d1;
        acc += h2 * d2;
        acc += h3 * d3;
    }
    for (; j < r1; ++j) {
        int s = col[j];
        acc += (float)H[(size_t)s * 64 + lane] * dis[s];
    }
    float di = dis[i];
    acc += (float)H[(size_t)i * 64 + lane] * di;
    O[(size_t)i * 64 + lane] = fmaxf(acc * di + bias[lane], 0.f);
}
__global__ void k_pool(const float* H, const int* batch, float* pool,
                       const int* flag, int nn) {
    int lane = threadIdx.x;
    int n0 = blockIdx.x * 256;
    if (n0 >= nn) return;
    int f = flag[0];
    int nend = (n0 + 256 < nn) ? n0 + 256 : nn;
    float acc = 0.f, cf = 0.f;
    int curg = rdi(batch, n0, f) & 63;
    for (int i = n0; i < nend; ++i) {
        int g = rdi(batch, i, f) & 63;
        if (g != curg) {
            atomicAdd(&pool[curg * 64 + lane], acc);
            if (lane == 0) atomicAdd(&pool[4096 + curg], cf);
            acc = 0.f; cf = 0.f; curg = g;
        }
        acc += H[(size_t)i * 64 + lane];
        cf += 1.f;
    }
    atomicAdd(&pool[curg * 64 + lane], acc);
    if (lane == 0) atomicAdd(&pool[4096 + curg], cf);
}
__global__ void k_mlp(const float* pool, const float* fW1, const float* fb1,
                      const float* fW2, const float* fb2, float* out) {
    __shared__ float w1[2048], w2[512], b1s[32], b2s[16], gm[4096];
    int t = threadIdx.x;
    for (int i = t; i < 2048; i += 256) w1[i] = fW1[i];
    for (int i = t; i < 512; i += 256) w2[i] = fW2[i];
    if (t < 32) b1s[t] = fb1[t];
    if (t < 16) b2s[t] = fb2[t];
    for (int i = t; i < 4096; i += 256) {
        float c = pool[4096 + (i >> 6)];
        gm[i] = pool[i] / ((c < 1.f) ? 1.f : c);
    }
    __syncthreads();
    if (t < 64) {
        float hid[32], lg[16];
        for (int j = 0; j < 32; ++j) {
            float s = b1s[j];
            for (int k = 0; k < 64; ++k) s += gm[t * 64 + k] * w1[k * 32 + j];
            hid[j] = fmaxf(s, 0.f);
        }
        float m = -1e30f;
        for (int j = 0; j < 16; ++j) {
            float s = b2s[j];
            for (int k = 0; k < 32; ++k) s += hid[k] * w2[k * 16 + j];
            lg[j] = s;
            m = fmaxf(m, s);
        }
        float se = 0.f;
        for (int j = 0; j < 16; ++j) se += expf(lg[j] - m);
        float lse = m + logf(se);
        for (int j = 0; j < 16; ++j) out[t * 16 + j] = lg[j] - lse;
    }
}

extern "C" void kernel_launch(void* const* d_in, const int* in_sizes, int n_in,
                              void* d_out, int out_size, void* d_ws, size_t ws_size,
                              hipStream_t stream) {
    (void)in_sizes; (void)n_in; (void)out_size;
    const int nn = 100000, ne = 1600000;
    const float* x   = (const float*)d_in[0];
    const int*   ei  = (const int*)d_in[1];
    const int*   bat = (const int*)d_in[2];
    const float* W1  = (const float*)d_in[3];
    const float* b1  = (const float*)d_in[4];
    const float* W2  = (const float*)d_in[5];
    const float* b2  = (const float*)d_in[6];
    const float* W3  = (const float*)d_in[7];
    const float* b3  = (const float*)d_in[8];
    const float* fW1 = (const float*)d_in[9];
    const float* fb1 = (const float*)d_in[10];
    const float* fW2 = (const float*)d_in[11];
    const float* fb2 = (const float*)d_in[12];
    float* out = (float*)d_out;   // f32 output

    char* ws = (char*)d_ws;
    size_t o = 0;
    int*      cnt  = (int*)(ws + o);      o += 400128;     // nn*4
    float*    pool = (float*)(ws + o);    o += 16896;      // 64*64 + 64
    size_t zints = o / 4;                                  // cnt+pool zero region
    int*      rowp = (int*)(ws + o);      o += 400384;     // (nn+1)*4
    int*      bsum = (int*)(ws + o);      o += 2048;
    float*    dis  = (float*)(ws + o);    o += 400128;
    int*      flag = (int*)(ws + o);      o += 256;
    _Float16* Wp1  = (_Float16*)(ws + o); o += 16384;      // 128*64 f16 packed
    _Float16* Wp2  = (_Float16*)(ws + o); o += 8192;       // 64*64 f16 packed
    _Float16* Wp3  = (_Float16*)(ws + o); o += 8192;
    int*      col  = (int*)(ws + o);      o += 6400000;    // ne*4
    _Float16* A    = (_Float16*)(ws + o); o += 12800000;   // nn*64*2 (f16 gather buf)
    float*    B    = (float*)(ws + o);    o += 25600000;   // nn*64*4
    if (ws_size < o) {
        k_mark<<<16, 64, 0, stream>>>(out, 150.0f);
        return;
    }

    int eb = (ne + 255) / 256, nb = (nn + 255) / 256;
    int mmb = nn / 16, aggb = (nn + 3) / 4;

    k_detect<<<1, 64, 0, stream>>>(ei, flag);
    k_zero<<<((int)zints + 255) / 256, 256, 0, stream>>>((int*)ws, (int)zints);
    k_count<<<eb, 256, 0, stream>>>(ei, cnt, flag, ne, nn);
    k_scan1<<<nb, 256, 0, stream>>>(cnt, rowp, bsum, dis, nn);
    k_scan2<<<1, 512, 0, stream>>>(bsum, nb);
    k_scan3<<<nb, 256, 0, stream>>>(rowp, bsum, nn);
    k_zero<<<nb, 256, 0, stream>>>(cnt, nn);         // cnt -> fill cursor
    k_fill<<<eb, 256, 0, stream>>>(ei, rowp, cnt, col, flag, ne, nn);

    k_pack<<<32, 256, 0, stream>>>(W1, Wp1, 128);
    k_pack<<<16, 256, 0, stream>>>(W2, Wp2, 64);
    k_pack<<<16, 256, 0, stream>>>(W3, Wp3, 64);

    // layer 1: x(f32) -> A(f16) -> B(f32)
    k_mm_mfma<<<mmb, 256, 0, stream>>>(x, Wp1, A, 128);
    k_agg<<<aggb, 256, 0, stream>>>(A, col, rowp, dis, b1, B, nn);
    // layer 2
    k_mm_mfma<<<mmb, 256, 0, stream>>>(B, Wp2, A, 64);
    k_agg<<<aggb, 256, 0, stream>>>(A, col, rowp, dis, b2, B, nn);
    // layer 3
    k_mm_mfma<<<mmb, 256, 0, stream>>>(B, Wp3, A, 64);
    k_agg<<<aggb, 256, 0, stream>>>(A, col, rowp, dis, b3, B, nn);

    k_pool<<<nb, 64, 0, stream>>>(B, bat, pool, flag, nn);
    k_mlp<<<1, 256, 0, stream>>>(pool, fW1, fb1, fW2, fb2, out);
}